// Round 1
// baseline (428.178 us; speedup 1.0000x reference)
//
#include <hip/hip_runtime.h>
#include <hip/hip_bf16.h>
#include <math.h>

#define D_HEAD 128
#define NBATCH 4
#define SEQ 2048

// workspace layout (float offsets)
#define WS_Q  0
#define WS_K  1048576
#define WS_V  2097152
#define WS_Y  3145728
#define WS_SQ 4194304
#define WS_OG 4202496
#define WS_LS 5251072
#define WS_GS 5259264
#define WS_END 5267456

// ---------------- projection: Q,K,V = x @ {Wq,Wk,Wv} ----------------
// grid 256 blocks x 256 thr; block computes 32 rows x 128 cols x 3 mats
__global__ __launch_bounds__(256) void proj_kernel(
    const float* __restrict__ x,
    const float* __restrict__ Wq, const float* __restrict__ Wk, const float* __restrict__ Wv,
    float* __restrict__ Q, float* __restrict__ K, float* __restrict__ V)
{
    __shared__ __align__(16) float Xs[32][36];
    __shared__ __align__(16) float Ws[3][32][128];
    const int t = threadIdx.x;
    const int row0 = blockIdx.x * 32;
    const int c4 = (t & 31) * 4;
    const int r4 = (t >> 5) * 4;
    const float* Wptr[3] = {Wq, Wk, Wv};
    float acc[3][4][4] = {};

    for (int k0 = 0; k0 < 1024; k0 += 32) {
        __syncthreads();
        {   // X tile 32x32
            int r = t >> 3, kc = (t & 7) * 4;
            *(float4*)&Xs[r][kc] = *(const float4*)&x[(size_t)(row0 + r) * 1024 + k0 + kc];
        }
        #pragma unroll
        for (int mm = 0; mm < 3; mm++) {
            #pragma unroll
            for (int j = 0; j < 4; j++) {
                int lin = t + j * 256;
                int kk = lin >> 5, cc = (lin & 31) * 4;
                *(float4*)&Ws[mm][kk][cc] = *(const float4*)&Wptr[mm][(size_t)(k0 + kk) * 128 + cc];
            }
        }
        __syncthreads();
        for (int kk = 0; kk < 32; kk++) {
            float xf[4];
            #pragma unroll
            for (int i = 0; i < 4; i++) xf[i] = Xs[r4 + i][kk];
            #pragma unroll
            for (int mm = 0; mm < 3; mm++) {
                const float4 wv = *(const float4*)&Ws[mm][kk][c4];
                #pragma unroll
                for (int i = 0; i < 4; i++) {
                    acc[mm][i][0] += xf[i] * wv.x;
                    acc[mm][i][1] += xf[i] * wv.y;
                    acc[mm][i][2] += xf[i] * wv.z;
                    acc[mm][i][3] += xf[i] * wv.w;
                }
            }
        }
    }
    float* Out[3] = {Q, K, V};
    #pragma unroll
    for (int mm = 0; mm < 3; mm++)
        #pragma unroll
        for (int i = 0; i < 4; i++)
            *(float4*)&Out[mm][(size_t)(row0 + r4 + i) * 128 + c4] =
                make_float4(acc[mm][i][0], acc[mm][i][1], acc[mm][i][2], acc[mm][i][3]);
}

// ---------------- y = K @ L_grav ; sq = rowsum(y*y) ----------------
// grid 512 blocks x 256 thr; block handles 16 rows
__global__ __launch_bounds__(256) void y_kernel(
    const float* __restrict__ K, const float* __restrict__ L,
    float* __restrict__ Y, float* __restrict__ SQ)
{
    __shared__ __align__(16) float Ls[128 * 128];
    __shared__ __align__(16) float Ks[16][132];
    const int t = threadIdx.x;
    const int row0 = blockIdx.x * 16;
    #pragma unroll
    for (int j = 0; j < 16; j++) {
        int lin = t + j * 256;
        ((float4*)Ls)[lin] = ((const float4*)L)[lin];
    }
    #pragma unroll
    for (int j = 0; j < 2; j++) {
        int lin = t + j * 256;
        int r = lin >> 5, dc = (lin & 31) * 4;
        *(float4*)&Ks[r][dc] = *(const float4*)&K[(size_t)(row0 + r) * 128 + dc];
    }
    __syncthreads();
    const int rl = t >> 4, c4 = (t & 15) * 4;
    float acc[8] = {};
    for (int d = 0; d < 128; d++) {
        const float kd = Ks[rl][d];
        const float4 l0 = *(const float4*)&Ls[d * 128 + c4];
        const float4 l1 = *(const float4*)&Ls[d * 128 + c4 + 64];
        acc[0] += kd * l0.x; acc[1] += kd * l0.y; acc[2] += kd * l0.z; acc[3] += kd * l0.w;
        acc[4] += kd * l1.x; acc[5] += kd * l1.y; acc[6] += kd * l1.z; acc[7] += kd * l1.w;
    }
    const int row = row0 + rl;
    *(float4*)&Y[(size_t)row * 128 + c4]      = make_float4(acc[0], acc[1], acc[2], acc[3]);
    *(float4*)&Y[(size_t)row * 128 + c4 + 64] = make_float4(acc[4], acc[5], acc[6], acc[7]);
    float s = 0.f;
    #pragma unroll
    for (int j = 0; j < 8; j++) s += acc[j] * acc[j];
    for (int off = 1; off < 16; off <<= 1) s += __shfl_xor(s, off, 64);
    if ((t & 15) == 0) SQ[row] = s;
}

// ---------------- fused dual attention (f32 baseline) ----------------
// 256 blocks: b(4) x h(2, key-tile parity) x jp(32, q-tile pair {jp, 63-jp})
__global__ __launch_bounds__(256, 1) void attn_kernel(
    const float* __restrict__ Q, const float* __restrict__ Km,
    const float* __restrict__ V, const float* __restrict__ Y,
    const float* __restrict__ SQ,
    float* __restrict__ OL, float* __restrict__ OG,
    float* __restrict__ LS, float* __restrict__ GS)
{
    __shared__ __align__(16) float Qs[32][132];
    __shared__ __align__(16) float Yqs[32][132];
    __shared__ __align__(16) float Ks[32][132];
    __shared__ __align__(16) float Ys[32][132];
    __shared__ __align__(16) float Vs[32][132];
    __shared__ __align__(16) float Pl[32][36];
    __shared__ __align__(16) float Pg[32][36];
    __shared__ float sqq[32];
    __shared__ float sqk[32];

    const int t  = threadIdx.x;
    const int bi = blockIdx.x;
    const int b  = bi & 3;
    const int h  = (bi >> 2) & 1;
    const int jp = bi >> 3;

    const int rl = t >> 3;        // 0..31: q-row within tile
    const int kb = t & 7;         // key lane group
    const int d4 = (t & 7) * 4;   // PV d-slice base

    const float* Qb  = Q  + (size_t)b * SEQ * D_HEAD;
    const float* Kb  = Km + (size_t)b * SEQ * D_HEAD;
    const float* Vb  = V  + (size_t)b * SEQ * D_HEAD;
    const float* Yb  = Y  + (size_t)b * SEQ * D_HEAD;
    const float* SQb = SQ + (size_t)b * SEQ;

    for (int m = 0; m < 2; m++) {
        const int qt = m ? (63 - jp) : jp;
        const int q0 = qt * 32;
        __syncthreads();
        #pragma unroll
        for (int j = 0; j < 4; j++) {
            int lin = t + j * 256;
            int r = lin >> 5, dc = (lin & 31) * 4;
            *(float4*)&Qs[r][dc]  = *(const float4*)&Qb[(size_t)(q0 + r) * D_HEAD + dc];
            *(float4*)&Yqs[r][dc] = *(const float4*)&Yb[(size_t)(q0 + r) * D_HEAD + dc];
        }
        if (t < 32) sqq[t] = SQb[q0 + t];

        float ol[16] = {}; float og[16] = {};
        float lsum = 0.f, gsum = 0.f;

        for (int kt = h; kt <= qt; kt += 2) {
            const int k0 = kt * 32;
            __syncthreads();   // prior tile PV done; Qs/sqq visible on first iter
            #pragma unroll
            for (int j = 0; j < 4; j++) {
                int lin = t + j * 256;
                int r = lin >> 5, dc = (lin & 31) * 4;
                *(float4*)&Ks[r][dc] = *(const float4*)&Kb[(size_t)(k0 + r) * D_HEAD + dc];
                *(float4*)&Ys[r][dc] = *(const float4*)&Yb[(size_t)(k0 + r) * D_HEAD + dc];
                *(float4*)&Vs[r][dc] = *(const float4*)&Vb[(size_t)(k0 + r) * D_HEAD + dc];
            }
            if (t < 32) sqk[t] = SQb[k0 + t];
            __syncthreads();

            // scores: thread -> row rl, keys kb+8j
            float sl[4] = {}; float sg[4] = {};
            for (int d = 0; d < 128; d += 4) {
                const float4 qv = *(const float4*)&Qs[rl][d];
                const float4 yq = *(const float4*)&Yqs[rl][d];
                #pragma unroll
                for (int j = 0; j < 4; j++) {
                    const int k = kb + 8 * j;
                    const float4 kv = *(const float4*)&Ks[k][d];
                    const float4 yv = *(const float4*)&Ys[k][d];
                    sl[j] += qv.x * kv.x + qv.y * kv.y + qv.z * kv.z + qv.w * kv.w;
                    sg[j] += yq.x * yv.x + yq.y * yv.y + yq.z * yv.z + yq.w * yv.w;
                }
            }
            const int qg = q0 + rl;
            #pragma unroll
            for (int j = 0; j < 4; j++) {
                const int k = kb + 8 * j;
                float pl = 0.f, pg = 0.f;
                if (k0 + k <= qg) {
                    pl = __expf(sl[j] * 0.088388347648318447f);    // 1/sqrt(128)
                    float d2 = sqq[rl] + sqk[k] - 2.f * sg[j];
                    d2 = fmaxf(d2, 0.f);
                    pg = __expf(d2 * (-0.00390625f));              // -1/256
                }
                Pl[rl][k] = pl;
                Pg[rl][k] = pg;
                lsum += pl; gsum += pg;
            }
            __syncthreads();   // P ready

            // PV: thread -> row rl, d-slices d4+32j
            for (int k = 0; k < 32; k++) {
                const float pl = Pl[rl][k];
                const float pg = Pg[rl][k];
                #pragma unroll
                for (int j = 0; j < 4; j++) {
                    const float4 vv = *(const float4*)&Vs[k][d4 + 32 * j];
                    ol[4*j+0] += pl * vv.x; ol[4*j+1] += pl * vv.y;
                    ol[4*j+2] += pl * vv.z; ol[4*j+3] += pl * vv.w;
                    og[4*j+0] += pg * vv.x; og[4*j+1] += pg * vv.y;
                    og[4*j+2] += pg * vv.z; og[4*j+3] += pg * vv.w;
                }
            }
        }

        // reduce row sums across the 8 lanes sharing rl
        for (int off = 1; off < 8; off <<= 1) {
            lsum += __shfl_xor(lsum, off, 64);
            gsum += __shfl_xor(gsum, off, 64);
        }
        const int row = b * SEQ + q0 + rl;
        if (kb == 0) {
            atomicAdd(&LS[row], lsum);
            atomicAdd(&GS[row], gsum);
        }
        #pragma unroll
        for (int j = 0; j < 4; j++)
            #pragma unroll
            for (int i = 0; i < 4; i++) {
                const int d = d4 + 32 * j + i;
                atomicAdd(&OL[(size_t)row * D_HEAD + d], ol[4*j+i]);
                atomicAdd(&OG[(size_t)row * D_HEAD + d], og[4*j+i]);
            }
    }
}

// ---------------- finalize: out = 0.7*OL/LS + 0.3*OG/(GS+1e-8) ----------------
__global__ __launch_bounds__(256) void finalize_kernel(
    float* __restrict__ out, const float* __restrict__ OG,
    const float* __restrict__ LS, const float* __restrict__ GS)
{
    const int i4 = blockIdx.x * 256 + threadIdx.x;   // 262144 float4s
    float4 o = ((float4*)out)[i4];
    const float4 g = ((const float4*)OG)[i4];
    const int row = i4 >> 5;
    const float wl = 0.7f / LS[row];
    const float wg = 0.3f / (GS[row] + 1e-8f);
    o.x = o.x * wl + g.x * wg;
    o.y = o.y * wl + g.y * wg;
    o.z = o.z * wl + g.z * wg;
    o.w = o.w * wl + g.w * wg;
    ((float4*)out)[i4] = o;
}

extern "C" void kernel_launch(void* const* d_in, const int* in_sizes, int n_in,
                              void* d_out, int out_size, void* d_ws, size_t ws_size,
                              hipStream_t stream) {
    const float* x  = (const float*)d_in[0];
    const float* Wq = (const float*)d_in[1];
    const float* Wk = (const float*)d_in[2];
    const float* Wv = (const float*)d_in[3];
    const float* Lg = (const float*)d_in[4];

    float* ws  = (float*)d_ws;
    float* Qw  = ws + WS_Q;
    float* Kw  = ws + WS_K;
    float* Vw  = ws + WS_V;
    float* Yw  = ws + WS_Y;
    float* SQw = ws + WS_SQ;
    float* OGw = ws + WS_OG;
    float* LSw = ws + WS_LS;
    float* GSw = ws + WS_GS;
    float* OLw = (float*)d_out;   // accumulate lang-PV directly into d_out

    hipMemsetAsync(d_out, 0, (size_t)out_size * sizeof(float), stream);
    hipMemsetAsync(OGw, 0, (size_t)(WS_END - WS_OG) * sizeof(float), stream);

    proj_kernel<<<256, 256, 0, stream>>>(x, Wq, Wk, Wv, Qw, Kw, Vw);
    y_kernel<<<512, 256, 0, stream>>>(Kw, Lg, Yw, SQw);
    attn_kernel<<<256, 256, 0, stream>>>(Qw, Kw, Vw, Yw, SQw, OLw, OGw, LSw, GSw);
    finalize_kernel<<<1024, 256, 0, stream>>>((float*)d_out, OGw, LSw, GSw);
}

// Round 2
// 280.891 us; speedup vs baseline: 1.5244x; 1.5244x over previous
//
#include <hip/hip_runtime.h>
#include <hip/hip_bf16.h>
#include <math.h>

typedef __attribute__((ext_vector_type(8))) short short8;
typedef __attribute__((ext_vector_type(4))) short s16x4;
typedef __attribute__((ext_vector_type(4))) float f32x4;

#define SEQ 2048
#define DH 128

__device__ __forceinline__ short f2bf(float f) {
    union { float f; unsigned u; } v; v.f = f;
    unsigned r = v.u + 0x7fffu + ((v.u >> 16) & 1u);
    return (short)(r >> 16);
}
__device__ __forceinline__ float bf2f(short s) {
    union { unsigned u; float f; } v; v.u = ((unsigned)(unsigned short)s) << 16;
    return v.f;
}

// ---------------- Wt[m][col 128][k 1024] bf16 = W[k][col] ----------------
__global__ __launch_bounds__(256) void wt_kernel(
    const float* __restrict__ Wq, const float* __restrict__ Wk, const float* __restrict__ Wv,
    short* __restrict__ Wt)
{
    __shared__ float Ls[64][65];
    const int t = threadIdx.x;
    const int m  = blockIdx.x >> 5;
    const int kb = (blockIdx.x >> 1) & 15;
    const int cb = blockIdx.x & 1;
    const float* W = m == 0 ? Wq : (m == 1 ? Wk : Wv);
    const int k0 = kb * 64, c0 = cb * 64;
    #pragma unroll
    for (int i = 0; i < 16; i++) {
        int lin = t + i * 256;
        int r = lin >> 6, c = lin & 63;
        Ls[r][c] = W[(k0 + r) * 128 + c0 + c];
    }
    __syncthreads();
    #pragma unroll
    for (int i = 0; i < 16; i++) {
        int lin = t + i * 256;
        int cc = lin >> 6, kk = lin & 63;
        Wt[(size_t)(m * 128 + c0 + cc) * 1024 + k0 + kk] = f2bf(Ls[kk][cc]);
    }
}

// ---------------- proj: Qh,Kh,Vh (bf16) = x @ W, MFMA ----------------
// 512 blocks x 64 thr; block = 16 rows x 3 mats x 128 cols
__global__ __launch_bounds__(64) void proj_kernel(
    const float* __restrict__ x, const short* __restrict__ Wt,
    short* __restrict__ Qh, short* __restrict__ Kh, short* __restrict__ Vh)
{
    const int l = threadIdx.x;
    const int c = l & 15, g = l >> 4;
    const int row0 = blockIdx.x * 16;
    f32x4 acc[3][8];
    #pragma unroll
    for (int m = 0; m < 3; m++)
        #pragma unroll
        for (int nt = 0; nt < 8; nt++) acc[m][nt] = (f32x4)0.f;

    for (int k0 = 0; k0 < 1024; k0 += 32) {
        const float* xp = &x[(size_t)(row0 + c) * 1024 + k0 + 8 * g];
        const float4 xa = *(const float4*)xp;
        const float4 xb = *(const float4*)(xp + 4);
        short8 af;
        af[0] = f2bf(xa.x); af[1] = f2bf(xa.y); af[2] = f2bf(xa.z); af[3] = f2bf(xa.w);
        af[4] = f2bf(xb.x); af[5] = f2bf(xb.y); af[6] = f2bf(xb.z); af[7] = f2bf(xb.w);
        #pragma unroll
        for (int m = 0; m < 3; m++) {
            const short* wb = &Wt[(size_t)(m * 128 + c) * 1024 + k0 + 8 * g];
            #pragma unroll
            for (int nt = 0; nt < 8; nt++) {
                const short8 bf = *(const short8*)(wb + (size_t)nt * 16 * 1024);
                acc[m][nt] = __builtin_amdgcn_mfma_f32_16x16x32_bf16(af, bf, acc[m][nt], 0, 0, 0);
            }
        }
    }
    short* Out[3] = {Qh, Kh, Vh};
    #pragma unroll
    for (int m = 0; m < 3; m++)
        #pragma unroll
        for (int nt = 0; nt < 8; nt++)
            #pragma unroll
            for (int r = 0; r < 4; r++)
                Out[m][(size_t)(row0 + 4 * g + r) * 128 + nt * 16 + c] = f2bf(acc[m][nt][r]);
}

// ---------------- y = K @ L (f32 acc), Yh bf16 + SQ from rounded y ----------------
__global__ __launch_bounds__(256) void y_kernel(
    const short* __restrict__ Kh, const float* __restrict__ L,
    short* __restrict__ Yh, float* __restrict__ SQ)
{
    __shared__ float Ls[128 * 128];
    __shared__ short Ks[16][128];
    const int t = threadIdx.x;
    const int row0 = blockIdx.x * 16;
    #pragma unroll
    for (int j = 0; j < 16; j++) {
        int lin = t + j * 256;
        ((float4*)Ls)[lin] = ((const float4*)L)[lin];
    }
    {
        int r = t >> 4, ch = t & 15;
        *(short8*)&Ks[r][ch * 8] = *(const short8*)&Kh[(size_t)(row0 + r) * 128 + ch * 8];
    }
    __syncthreads();
    const int rl = t >> 4, c4 = (t & 15) * 4;
    float acc[8] = {};
    for (int d = 0; d < 128; d++) {
        const float kd = bf2f(Ks[rl][d]);
        const float4 l0 = *(const float4*)&Ls[d * 128 + c4];
        const float4 l1 = *(const float4*)&Ls[d * 128 + c4 + 64];
        acc[0] += kd * l0.x; acc[1] += kd * l0.y; acc[2] += kd * l0.z; acc[3] += kd * l0.w;
        acc[4] += kd * l1.x; acc[5] += kd * l1.y; acc[6] += kd * l1.z; acc[7] += kd * l1.w;
    }
    const int row = row0 + rl;
    s16x4 h0, h1;
    float s = 0.f;
    #pragma unroll
    for (int j = 0; j < 4; j++) {
        short h = f2bf(acc[j]);     float rv = bf2f(h); s += rv * rv; h0[j] = h;
        short g = f2bf(acc[j + 4]); float gv = bf2f(g); s += gv * gv; h1[j] = g;
    }
    *(s16x4*)&Yh[(size_t)row * 128 + c4]      = h0;
    *(s16x4*)&Yh[(size_t)row * 128 + c4 + 64] = h1;
    for (int off = 1; off < 16; off <<= 1) s += __shfl_xor(s, off);
    if ((t & 15) == 0) SQ[row] = s;
}

// ---------------- Vt[b][d 128][key 2048] = Vh[b][key][d] ----------------
__global__ __launch_bounds__(256) void vt_kernel(
    const short* __restrict__ Vh, short* __restrict__ Vt)
{
    __shared__ short Ls[64][72];
    const int t = threadIdx.x;
    const int b  = blockIdx.x >> 6;
    const int nb = (blockIdx.x >> 1) & 31;
    const int db = blockIdx.x & 1;
    const int n0 = nb * 64, d0 = db * 64;
    const short* Vb = Vh + (size_t)b * SEQ * 128;
    short* Vtb = Vt + (size_t)b * 128 * SEQ;
    #pragma unroll
    for (int i = 0; i < 2; i++) {
        int row = (t >> 3) + 32 * i;
        int ch = t & 7;
        *(short8*)&Ls[row][ch * 8] = *(const short8*)&Vb[(size_t)(n0 + row) * 128 + d0 + ch * 8];
    }
    __syncthreads();
    #pragma unroll
    for (int i = 0; i < 2; i++) {
        int dd = (t >> 3) + 32 * i;
        int nc = t & 7;
        short8 v;
        #pragma unroll
        for (int j = 0; j < 8; j++) v[j] = Ls[nc * 8 + j][dd];
        *(short8*)&Vtb[(size_t)(d0 + dd) * SEQ + n0 + nc * 8] = v;
    }
}

// ---------------- fused dual attention, MFMA ----------------
// 2048 1-wave blocks: grav(2) x jp(32) x s(8) x b(4)
__global__ __launch_bounds__(64) void attn_kernel(
    const short* __restrict__ Qh, const short* __restrict__ Kh,
    const short* __restrict__ Yh, const short* __restrict__ Vt,
    const float* __restrict__ SQv,
    float* __restrict__ OL, float* __restrict__ OG,
    float* __restrict__ LS, float* __restrict__ GS)
{
    __shared__ short P[32 * 64];   // bf16 probs, XOR-swizzled rows
    const int l = threadIdx.x;
    const int c = l & 15, g = l >> 4;
    const int bid = blockIdx.x;
    const int grav = bid >> 10;
    const int rest = bid & 1023;
    const int b = rest & 3;
    const int s = (rest >> 2) & 7;
    const int jp = rest >> 5;

    const size_t boff = (size_t)b * SEQ * 128;
    const short* Ab = (grav ? Yh : Qh) + boff;   // query-side rows
    const short* Bb = (grav ? Yh : Kh) + boff;   // key-side rows
    const short* Vb = Vt + boff;                 // [128][2048]
    const float* SQb = SQv + b * SEQ;
    float* O  = grav ? OG : OL;
    float* RS = grav ? GS : LS;

    for (int m = 0; m < 2; m++) {
        const int qt = m ? 63 - jp : jp;
        const int q0 = qt * 32;
        const int nkt = (qt + 2) >> 1;   // # 64-key tiles

        short8 qf[2][4];
        #pragma unroll
        for (int mt = 0; mt < 2; mt++)
            #pragma unroll
            for (int kc = 0; kc < 4; kc++)
                qf[mt][kc] = *(const short8*)&Ab[(size_t)(q0 + mt * 16 + c) * 128 + kc * 32 + 8 * g];

        float sqq[2][4];
        if (grav) {
            #pragma unroll
            for (int mt = 0; mt < 2; mt++)
                #pragma unroll
                for (int r = 0; r < 4; r++)
                    sqq[mt][r] = SQb[q0 + mt * 16 + 4 * g + r];
        }

        f32x4 acc[2][8];
        #pragma unroll
        for (int mt = 0; mt < 2; mt++)
            #pragma unroll
            for (int dt = 0; dt < 8; dt++) acc[mt][dt] = (f32x4)0.f;
        float rsum[2][4] = {};

        for (int tt = s; tt < nkt; tt += 8) {
            const int k0 = tt * 64;
            #pragma unroll
            for (int kt = 0; kt < 4; kt++) {
                const int kbase = k0 + kt * 16;
                if (kbase <= q0 + 31) {
                    short8 bf[4];
                    #pragma unroll
                    for (int kc = 0; kc < 4; kc++)
                        bf[kc] = *(const short8*)&Bb[(size_t)(kbase + c) * 128 + kc * 32 + 8 * g];
                    const float sqk = grav ? SQb[kbase + c] : 0.f;
                    #pragma unroll
                    for (int mt = 0; mt < 2; mt++) {
                        f32x4 sc = (f32x4)0.f;
                        #pragma unroll
                        for (int kc = 0; kc < 4; kc++)
                            sc = __builtin_amdgcn_mfma_f32_16x16x32_bf16(qf[mt][kc], bf[kc], sc, 0, 0, 0);
                        #pragma unroll
                        for (int r = 0; r < 4; r++) {
                            const int qrow = q0 + mt * 16 + 4 * g + r;
                            const int key = kbase + c;
                            float p = 0.f;
                            if (key <= qrow) {
                                if (grav) {
                                    float d2 = sqq[mt][r] + sqk - 2.f * sc[r];
                                    d2 = fmaxf(d2, 0.f);
                                    p = __expf(d2 * -0.00390625f);    // -1/(2*128)
                                } else {
                                    p = __expf(sc[r] * 0.08838834764831845f);  // 1/sqrt(128)
                                }
                            }
                            const short ph = f2bf(p);
                            rsum[mt][r] += bf2f(ph);
                            const int row = mt * 16 + 4 * g + r;
                            P[((row * 128 + (kt * 16 + c) * 2) ^ ((row & 7) << 4)) >> 1] = ph;
                        }
                    }
                } else {
                    #pragma unroll
                    for (int mt = 0; mt < 2; mt++)
                        #pragma unroll
                        for (int r = 0; r < 4; r++) {
                            const int row = mt * 16 + 4 * g + r;
                            P[((row * 128 + (kt * 16 + c) * 2) ^ ((row & 7) << 4)) >> 1] = 0;
                        }
                }
            }
            __syncthreads();
            short8 pf[2][2];
            #pragma unroll
            for (int mt = 0; mt < 2; mt++)
                #pragma unroll
                for (int kc = 0; kc < 2; kc++) {
                    const int row = mt * 16 + c;
                    const int off = (row * 128 + 16 * g + 64 * kc) ^ ((row & 7) << 4);
                    pf[mt][kc] = *(const short8*)((const char*)P + off);
                }
            #pragma unroll
            for (int dt = 0; dt < 8; dt++) {
                #pragma unroll
                for (int kc = 0; kc < 2; kc++) {
                    const short8 vf = *(const short8*)&Vb[(size_t)(dt * 16 + c) * SEQ + k0 + kc * 32 + 8 * g];
                    #pragma unroll
                    for (int mt = 0; mt < 2; mt++)
                        acc[mt][dt] = __builtin_amdgcn_mfma_f32_16x16x32_bf16(pf[mt][kc], vf, acc[mt][dt], 0, 0, 0);
                }
            }
            __syncthreads();
        }

        #pragma unroll
        for (int mt = 0; mt < 2; mt++)
            #pragma unroll
            for (int r = 0; r < 4; r++) {
                float v = rsum[mt][r];
                v += __shfl_xor(v, 1); v += __shfl_xor(v, 2);
                v += __shfl_xor(v, 4); v += __shfl_xor(v, 8);
                rsum[mt][r] = v;
            }
        if (c == 0) {
            #pragma unroll
            for (int mt = 0; mt < 2; mt++)
                #pragma unroll
                for (int r = 0; r < 4; r++)
                    atomicAdd(&RS[b * SEQ + q0 + mt * 16 + 4 * g + r], rsum[mt][r]);
        }
        #pragma unroll
        for (int mt = 0; mt < 2; mt++)
            #pragma unroll
            for (int dt = 0; dt < 8; dt++)
                #pragma unroll
                for (int r = 0; r < 4; r++)
                    atomicAdd(&O[boff + (size_t)(q0 + mt * 16 + 4 * g + r) * 128 + dt * 16 + c],
                              acc[mt][dt][r]);
    }
}

// ---------------- finalize: out = 0.7*OL/LS + 0.3*OG/(GS+1e-8) ----------------
__global__ __launch_bounds__(256) void finalize_kernel(
    float* __restrict__ out, const float* __restrict__ OG,
    const float* __restrict__ LS, const float* __restrict__ GS)
{
    const int i4 = blockIdx.x * 256 + threadIdx.x;
    float4 o = ((float4*)out)[i4];
    const float4 gv = ((const float4*)OG)[i4];
    const int row = i4 >> 5;
    const float wl = 0.7f / LS[row];
    const float wg = 0.3f / (GS[row] + 1e-8f);
    o.x = o.x * wl + gv.x * wg;
    o.y = o.y * wl + gv.y * wg;
    o.z = o.z * wl + gv.z * wg;
    o.w = o.w * wl + gv.w * wg;
    ((float4*)out)[i4] = o;
}

extern "C" void kernel_launch(void* const* d_in, const int* in_sizes, int n_in,
                              void* d_out, int out_size, void* d_ws, size_t ws_size,
                              hipStream_t stream) {
    const float* x  = (const float*)d_in[0];
    const float* Wq = (const float*)d_in[1];
    const float* Wk = (const float*)d_in[2];
    const float* Wv = (const float*)d_in[3];
    const float* Lg = (const float*)d_in[4];

    char* ws = (char*)d_ws;
    short* Qh  = (short*)(ws + 0);
    short* Kh  = (short*)(ws + 2097152);
    short* Vh  = (short*)(ws + 4194304);
    short* Yh  = (short*)(ws + 6291456);
    short* Vt  = (short*)(ws + 8388608);
    short* Wt  = (short*)(ws + 10485760);
    float* SQv = (float*)(ws + 11272192);
    float* LS  = (float*)(ws + 11304960);
    float* GS  = (float*)(ws + 11337728);   // contiguous after LS
    float* OG  = (float*)(ws + 11370496);
    float* OL  = (float*)d_out;

    hipMemsetAsync(d_out, 0, 4194304, stream);
    hipMemsetAsync((void*)LS, 0, 65536, stream);
    hipMemsetAsync((void*)OG, 0, 4194304, stream);

    wt_kernel<<<96, 256, 0, stream>>>(Wq, Wk, Wv, Wt);
    proj_kernel<<<512, 64, 0, stream>>>(x, Wt, Qh, Kh, Vh);
    y_kernel<<<512, 256, 0, stream>>>(Kh, Lg, Yh, SQv);
    vt_kernel<<<256, 256, 0, stream>>>(Vh, Vt);
    attn_kernel<<<2048, 64, 0, stream>>>(Qh, Kh, Yh, Vt, SQv, OL, OG, LS, GS);
    finalize_kernel<<<1024, 256, 0, stream>>>((float*)d_out, OG, LS, GS);
}

// Round 3
// 121.738 us; speedup vs baseline: 3.5172x; 2.3073x over previous
//
#include <hip/hip_runtime.h>
#include <hip/hip_bf16.h>
#include <math.h>

typedef __attribute__((ext_vector_type(8))) short short8;
typedef __attribute__((ext_vector_type(4))) short s16x4;
typedef __attribute__((ext_vector_type(4))) float f32x4;

#define SEQ 2048
#define DH 128

__device__ __forceinline__ short f2bf(float f) {
    union { float f; unsigned u; } v; v.f = f;
    unsigned r = v.u + 0x7fffu + ((v.u >> 16) & 1u);
    return (short)(r >> 16);
}
__device__ __forceinline__ float bf2f(short s) {
    union { unsigned u; float f; } v; v.u = ((unsigned)(unsigned short)s) << 16;
    return v.f;
}

__device__ __forceinline__ void gll16(const void* g, void* l) {
    __builtin_amdgcn_global_load_lds(
        (const __attribute__((address_space(1))) unsigned int*)g,
        (__attribute__((address_space(3))) unsigned int*)l, 16, 0, 0);
}

// ---------------- Wt2: frag-linear bf16 W ----------------
// layout: [m][ks 16][idx16 1024][8 shorts]; idx16 = (colTile*2+kc)*64 + g*16 + c
// element (col = colTile*16+c, k = ks*64 + kc*32 + g*8 + e)
__global__ __launch_bounds__(256) void wt_kernel(
    const float* __restrict__ Wq, const float* __restrict__ Wk, const float* __restrict__ Wv,
    short* __restrict__ Wt2)
{
    const int t = threadIdx.x;
    const int m  = blockIdx.x >> 4;
    const int ks = blockIdx.x & 15;
    const float* W = m == 0 ? Wq : (m == 1 ? Wk : Wv);
    short* dst = Wt2 + ((size_t)(m * 16 + ks) * 1024) * 8;
    #pragma unroll
    for (int j = 0; j < 4; j++) {
        const int idx = t * 4 + j;
        const int ctile = idx >> 7;
        const int kc = (idx >> 6) & 1;
        const int gg = (idx >> 4) & 3;
        const int cc = idx & 15;
        const int col = ctile * 16 + cc;
        const int kb = ks * 64 + kc * 32 + gg * 8;
        short8 h;
        #pragma unroll
        for (int e = 0; e < 8; e++) h[e] = f2bf(W[(size_t)(kb + e) * 128 + col]);
        *(short8*)&dst[idx * 8] = h;
    }
}

// ---------------- proj: Qh,Kh,Vh (bf16) = x @ W, tiled MFMA ----------------
// 768 blocks (256 rowtiles x 3 mats) x 256 thr (4 waves); block = 32 rows x 128 cols
__global__ __launch_bounds__(256) void proj_kernel(
    const float* __restrict__ x, const short* __restrict__ Wt2,
    short* __restrict__ Qh, short* __restrict__ Kh, short* __restrict__ Vh)
{
    __shared__ short Xs[2048];   // 4 KB frag-linear: (rowTile*2+kc)*64 + lane
    __shared__ short Ws[8192];   // 16 KB frag-linear: (colTile*2+kc)*64 + lane
    const int t = threadIdx.x;
    const int w = t >> 6, l = t & 63;
    const int c = l & 15, g = l >> 4;
    const int bid = blockIdx.x;
    const int m = bid % 3;
    const int row0 = (bid / 3) * 32;
    const short* Wm = Wt2 + (size_t)m * 16 * 1024 * 8;

    // X staging map (fixed per thread): row xr, k-chunk xk
    const int xr = t >> 3;
    const int xk = (t & 7) * 8;
    const int xIdx = ((xr >> 4) * 2 + (xk >> 5)) * 64 + ((xk >> 3) & 3) * 16 + (xr & 15);

    const int rt = w & 1;          // A row-tile for this wave
    const int ct4 = (w >> 1) * 4;  // B col-tile base (4 tiles/wave)
    f32x4 acc[4];
    #pragma unroll
    for (int nt = 0; nt < 4; nt++) acc[nt] = (f32x4)0.f;

    for (int ks = 0; ks < 16; ks++) {
        __syncthreads();
        // stage W: linear copy via global_load_lds (wave-uniform dst)
        const short* wsrc = Wm + ((size_t)ks * 1024 + w * 256 + l) * 8;
        #pragma unroll
        for (int j = 0; j < 4; j++)
            gll16(wsrc + j * 64 * 8, (void*)&Ws[(w * 256 + j * 64) * 8]);
        // stage X: coalesced f32 load -> bf16 -> frag-linear LDS
        {
            const float* xp = &x[(size_t)(row0 + xr) * 1024 + ks * 64 + xk];
            const float4 a = *(const float4*)xp;
            const float4 b = *(const float4*)(xp + 4);
            short8 h;
            h[0] = f2bf(a.x); h[1] = f2bf(a.y); h[2] = f2bf(a.z); h[3] = f2bf(a.w);
            h[4] = f2bf(b.x); h[5] = f2bf(b.y); h[6] = f2bf(b.z); h[7] = f2bf(b.w);
            *(short8*)&Xs[xIdx * 8] = h;
        }
        __syncthreads();
        #pragma unroll
        for (int kc = 0; kc < 2; kc++) {
            const short8 af = *(const short8*)&Xs[((rt * 2 + kc) * 64 + l) * 8];
            #pragma unroll
            for (int nt = 0; nt < 4; nt++) {
                const short8 bf = *(const short8*)&Ws[(((ct4 + nt) * 2 + kc) * 64 + l) * 8];
                acc[nt] = __builtin_amdgcn_mfma_f32_16x16x32_bf16(af, bf, acc[nt], 0, 0, 0);
            }
        }
    }
    short* Out = m == 0 ? Qh : (m == 1 ? Kh : Vh);
    #pragma unroll
    for (int nt = 0; nt < 4; nt++)
        #pragma unroll
        for (int r = 0; r < 4; r++)
            Out[(size_t)(row0 + rt * 16 + 4 * g + r) * 128 + (ct4 + nt) * 16 + c] = f2bf(acc[nt][r]);
}

// ---------------- y = K @ L (f32 acc), Yh bf16 + SQ from rounded y ----------------
__global__ __launch_bounds__(256) void y_kernel(
    const short* __restrict__ Kh, const float* __restrict__ L,
    short* __restrict__ Yh, float* __restrict__ SQ)
{
    __shared__ float Ls[128 * 128];
    __shared__ short Ks[16][128];
    const int t = threadIdx.x;
    const int row0 = blockIdx.x * 16;
    #pragma unroll
    for (int j = 0; j < 16; j++) {
        int lin = t + j * 256;
        ((float4*)Ls)[lin] = ((const float4*)L)[lin];
    }
    {
        int r = t >> 4, ch = t & 15;
        *(short8*)&Ks[r][ch * 8] = *(const short8*)&Kh[(size_t)(row0 + r) * 128 + ch * 8];
    }
    __syncthreads();
    const int rl = t >> 4, c4 = (t & 15) * 4;
    float acc[8] = {};
    for (int d = 0; d < 128; d++) {
        const float kd = bf2f(Ks[rl][d]);
        const float4 l0 = *(const float4*)&Ls[d * 128 + c4];
        const float4 l1 = *(const float4*)&Ls[d * 128 + c4 + 64];
        acc[0] += kd * l0.x; acc[1] += kd * l0.y; acc[2] += kd * l0.z; acc[3] += kd * l0.w;
        acc[4] += kd * l1.x; acc[5] += kd * l1.y; acc[6] += kd * l1.z; acc[7] += kd * l1.w;
    }
    const int row = row0 + rl;
    s16x4 h0, h1;
    float s = 0.f;
    #pragma unroll
    for (int j = 0; j < 4; j++) {
        short h = f2bf(acc[j]);     float rv = bf2f(h); s += rv * rv; h0[j] = h;
        short g = f2bf(acc[j + 4]); float gv = bf2f(g); s += gv * gv; h1[j] = g;
    }
    *(s16x4*)&Yh[(size_t)row * 128 + c4]      = h0;
    *(s16x4*)&Yh[(size_t)row * 128 + c4 + 64] = h1;
    for (int off = 1; off < 16; off <<= 1) s += __shfl_xor(s, off);
    if ((t & 15) == 0) SQ[row] = s;
}

// ---------------- Vt[b][d 128][key 2048] = Vh[b][key][d] ----------------
__global__ __launch_bounds__(256) void vt_kernel(
    const short* __restrict__ Vh, short* __restrict__ Vt)
{
    __shared__ short Ls[64][72];
    const int t = threadIdx.x;
    const int b  = blockIdx.x >> 6;
    const int nb = (blockIdx.x >> 1) & 31;
    const int db = blockIdx.x & 1;
    const int n0 = nb * 64, d0 = db * 64;
    const short* Vb = Vh + (size_t)b * SEQ * 128;
    short* Vtb = Vt + (size_t)b * 128 * SEQ;
    #pragma unroll
    for (int i = 0; i < 2; i++) {
        int row = (t >> 3) + 32 * i;
        int ch = t & 7;
        *(short8*)&Ls[row][ch * 8] = *(const short8*)&Vb[(size_t)(n0 + row) * 128 + d0 + ch * 8];
    }
    __syncthreads();
    #pragma unroll
    for (int i = 0; i < 2; i++) {
        int dd = (t >> 3) + 32 * i;
        int nc = t & 7;
        short8 v;
        #pragma unroll
        for (int j = 0; j < 8; j++) v[j] = Ls[nc * 8 + j][dd];
        *(short8*)&Vtb[(size_t)(d0 + dd) * SEQ + n0 + nc * 8] = v;
    }
}

// ---------------- fused dual attention, MFMA ----------------
// 2048 1-wave blocks: grav(2) x jp(32) x s(8) x b(4)
__global__ __launch_bounds__(64) void attn_kernel(
    const short* __restrict__ Qh, const short* __restrict__ Kh,
    const short* __restrict__ Yh, const short* __restrict__ Vt,
    const float* __restrict__ SQv,
    float* __restrict__ OL, float* __restrict__ OG,
    float* __restrict__ LS, float* __restrict__ GS)
{
    __shared__ short P[32 * 64];   // bf16 probs, XOR-swizzled rows
    const int l = threadIdx.x;
    const int c = l & 15, g = l >> 4;
    const int bid = blockIdx.x;
    const int grav = bid >> 10;
    const int rest = bid & 1023;
    const int b = rest & 3;
    const int s = (rest >> 2) & 7;
    const int jp = rest >> 5;

    const size_t boff = (size_t)b * SEQ * 128;
    const short* Ab = (grav ? Yh : Qh) + boff;   // query-side rows
    const short* Bb = (grav ? Yh : Kh) + boff;   // key-side rows
    const short* Vb = Vt + boff;                 // [128][2048]
    const float* SQb = SQv + b * SEQ;
    float* O  = grav ? OG : OL;
    float* RS = grav ? GS : LS;

    for (int m = 0; m < 2; m++) {
        const int qt = m ? 63 - jp : jp;
        const int q0 = qt * 32;
        const int nkt = (qt + 2) >> 1;   // # 64-key tiles

        short8 qf[2][4];
        #pragma unroll
        for (int mt = 0; mt < 2; mt++)
            #pragma unroll
            for (int kc = 0; kc < 4; kc++)
                qf[mt][kc] = *(const short8*)&Ab[(size_t)(q0 + mt * 16 + c) * 128 + kc * 32 + 8 * g];

        float sqq[2][4];
        if (grav) {
            #pragma unroll
            for (int mt = 0; mt < 2; mt++)
                #pragma unroll
                for (int r = 0; r < 4; r++)
                    sqq[mt][r] = SQb[q0 + mt * 16 + 4 * g + r];
        }

        f32x4 acc[2][8];
        #pragma unroll
        for (int mt = 0; mt < 2; mt++)
            #pragma unroll
            for (int dt = 0; dt < 8; dt++) acc[mt][dt] = (f32x4)0.f;
        float rsum[2][4] = {};

        for (int tt = s; tt < nkt; tt += 8) {
            const int k0 = tt * 64;
            #pragma unroll
            for (int kt = 0; kt < 4; kt++) {
                const int kbase = k0 + kt * 16;
                if (kbase <= q0 + 31) {
                    short8 bf[4];
                    #pragma unroll
                    for (int kc = 0; kc < 4; kc++)
                        bf[kc] = *(const short8*)&Bb[(size_t)(kbase + c) * 128 + kc * 32 + 8 * g];
                    const float sqk = grav ? SQb[kbase + c] : 0.f;
                    #pragma unroll
                    for (int mt = 0; mt < 2; mt++) {
                        f32x4 sc = (f32x4)0.f;
                        #pragma unroll
                        for (int kc = 0; kc < 4; kc++)
                            sc = __builtin_amdgcn_mfma_f32_16x16x32_bf16(qf[mt][kc], bf[kc], sc, 0, 0, 0);
                        #pragma unroll
                        for (int r = 0; r < 4; r++) {
                            const int qrow = q0 + mt * 16 + 4 * g + r;
                            const int key = kbase + c;
                            float p = 0.f;
                            if (key <= qrow) {
                                if (grav) {
                                    float d2 = sqq[mt][r] + sqk - 2.f * sc[r];
                                    d2 = fmaxf(d2, 0.f);
                                    p = __expf(d2 * -0.00390625f);    // -1/(2*128)
                                } else {
                                    p = __expf(sc[r] * 0.08838834764831845f);  // 1/sqrt(128)
                                }
                            }
                            const short ph = f2bf(p);
                            rsum[mt][r] += bf2f(ph);
                            const int row = mt * 16 + 4 * g + r;
                            P[((row * 128 + (kt * 16 + c) * 2) ^ ((row & 7) << 4)) >> 1] = ph;
                        }
                    }
                } else {
                    #pragma unroll
                    for (int mt = 0; mt < 2; mt++)
                        #pragma unroll
                        for (int r = 0; r < 4; r++) {
                            const int row = mt * 16 + 4 * g + r;
                            P[((row * 128 + (kt * 16 + c) * 2) ^ ((row & 7) << 4)) >> 1] = 0;
                        }
                }
            }
            __syncthreads();
            short8 pf[2][2];
            #pragma unroll
            for (int mt = 0; mt < 2; mt++)
                #pragma unroll
                for (int kc = 0; kc < 2; kc++) {
                    const int row = mt * 16 + c;
                    const int off = (row * 128 + 16 * g + 64 * kc) ^ ((row & 7) << 4);
                    pf[mt][kc] = *(const short8*)((const char*)P + off);
                }
            #pragma unroll
            for (int dt = 0; dt < 8; dt++) {
                #pragma unroll
                for (int kc = 0; kc < 2; kc++) {
                    const short8 vf = *(const short8*)&Vb[(size_t)(dt * 16 + c) * SEQ + k0 + kc * 32 + 8 * g];
                    #pragma unroll
                    for (int mt = 0; mt < 2; mt++)
                        acc[mt][dt] = __builtin_amdgcn_mfma_f32_16x16x32_bf16(pf[mt][kc], vf, acc[mt][dt], 0, 0, 0);
                }
            }
            __syncthreads();
        }

        #pragma unroll
        for (int mt = 0; mt < 2; mt++)
            #pragma unroll
            for (int r = 0; r < 4; r++) {
                float v = rsum[mt][r];
                v += __shfl_xor(v, 1); v += __shfl_xor(v, 2);
                v += __shfl_xor(v, 4); v += __shfl_xor(v, 8);
                rsum[mt][r] = v;
            }
        if (c == 0) {
            #pragma unroll
            for (int mt = 0; mt < 2; mt++)
                #pragma unroll
                for (int r = 0; r < 4; r++)
                    atomicAdd(&RS[b * SEQ + q0 + mt * 16 + 4 * g + r], rsum[mt][r]);
        }
        #pragma unroll
        for (int mt = 0; mt < 2; mt++)
            #pragma unroll
            for (int dt = 0; dt < 8; dt++)
                #pragma unroll
                for (int r = 0; r < 4; r++)
                    atomicAdd(&O[boff + (size_t)(q0 + mt * 16 + 4 * g + r) * 128 + dt * 16 + c],
                              acc[mt][dt][r]);
    }
}

// ---------------- finalize: out = 0.7*OL/LS + 0.3*OG/(GS+1e-8) ----------------
__global__ __launch_bounds__(256) void finalize_kernel(
    float* __restrict__ out, const float* __restrict__ OG,
    const float* __restrict__ LS, const float* __restrict__ GS)
{
    const int i4 = blockIdx.x * 256 + threadIdx.x;
    float4 o = ((float4*)out)[i4];
    const float4 gv = ((const float4*)OG)[i4];
    const int row = i4 >> 5;
    const float wl = 0.7f / LS[row];
    const float wg = 0.3f / (GS[row] + 1e-8f);
    o.x = o.x * wl + gv.x * wg;
    o.y = o.y * wl + gv.y * wg;
    o.z = o.z * wl + gv.z * wg;
    o.w = o.w * wl + gv.w * wg;
    ((float4*)out)[i4] = o;
}

extern "C" void kernel_launch(void* const* d_in, const int* in_sizes, int n_in,
                              void* d_out, int out_size, void* d_ws, size_t ws_size,
                              hipStream_t stream) {
    const float* x  = (const float*)d_in[0];
    const float* Wq = (const float*)d_in[1];
    const float* Wk = (const float*)d_in[2];
    const float* Wv = (const float*)d_in[3];
    const float* Lg = (const float*)d_in[4];

    char* ws = (char*)d_ws;
    short* Qh  = (short*)(ws + 0);
    short* Kh  = (short*)(ws + 2097152);
    short* Vh  = (short*)(ws + 4194304);
    short* Yh  = (short*)(ws + 6291456);
    short* Vt  = (short*)(ws + 8388608);
    short* Wt2 = (short*)(ws + 10485760);
    float* SQv = (float*)(ws + 11272192);
    float* LS  = (float*)(ws + 11304960);
    float* GS  = (float*)(ws + 11337728);   // contiguous after LS
    float* OG  = (float*)(ws + 11370496);
    float* OL  = (float*)d_out;

    hipMemsetAsync(d_out, 0, 4194304, stream);
    hipMemsetAsync((void*)LS, 0, 65536, stream);
    hipMemsetAsync((void*)OG, 0, 4194304, stream);

    wt_kernel<<<48, 256, 0, stream>>>(Wq, Wk, Wv, Wt2);
    proj_kernel<<<768, 256, 0, stream>>>(x, Wt2, Qh, Kh, Vh);
    y_kernel<<<512, 256, 0, stream>>>(Kh, Lg, Yh, SQv);
    vt_kernel<<<256, 256, 0, stream>>>(Vh, Vt);
    attn_kernel<<<2048, 64, 0, stream>>>(Qh, Kh, Yh, Vt, SQv, OL, OG, LS, GS);
    finalize_kernel<<<1024, 256, 0, stream>>>((float*)d_out, OG, LS, GS);
}